// Round 18
// baseline (138.642 us; speedup 1.0000x reference)
//
#include <hip/hip_runtime.h>

// Involution via bf16 MFMA tap-GEMM, operand-swapped (D[t][px]), 32x32x16.
// R18: (a) revert R17's hb pipeline (neutral, +16 VGPR); (b) quarter-row
// blocks: y0 = 16*blockIdx.y, x_s [22][72], hs_s [22][64] (LDS 20.5->11.7KB),
// grid 2048->4096 -> more co-resident blocks per CU for cross-block latency
// overlap; per-block serial prologue halves. hv1/hv2 split kept (R17-proven).

#define C_    256
#define HID_  64
#define KS_   7
#define KK_   49
#define G_    256
#define H_    64
#define W_    64
#define HW_   4096
#define BN_EPS 1e-5f

typedef __attribute__((ext_vector_type(8)))  short bf16x8;
typedef __attribute__((ext_vector_type(4)))  float f32x4;
typedef __attribute__((ext_vector_type(16))) float f32x16;
typedef __attribute__((ext_vector_type(2)))  unsigned uv2;

__device__ __forceinline__ ushort f2bf(float f) {
    unsigned u = __float_as_uint(f);
    return (ushort)((u + 0x7fffu + ((u >> 16) & 1u)) >> 16);   // RNE
}
__device__ __forceinline__ float bf2f(ushort s) {
    return __uint_as_float((unsigned)s << 16);
}
// v[lane^32] on the VALU pipe, direction-agnostic (pairsum - own). Proven R14/15.
__device__ __forceinline__ float xor32p(float v) {
#if __has_builtin(__builtin_amdgcn_permlane32_swap)
    uv2 r = __builtin_amdgcn_permlane32_swap(__float_as_uint(v), __float_as_uint(v),
                                             false, false);
    return (__uint_as_float(r[0]) + __uint_as_float(r[1])) - v;
#else
    return __shfl_xor(v, 32);
#endif
}

// ---------------------------------------------------------------- prep ----
// Layout: t' = i*8 + j (i,j<7 valid); t'&7==7 -> zero row; t'>=56 -> u-region.
// blocks 0..255:  kwb[g][t'][k] bf16 (valid rows + j=7 zeros; skip t'>=56)
// block 256:      rwT[k][o] = reduce_w[o][k]*bn_inv[o]; betp[o]
// block 257:      kbp[g][t'] = bias (valid), 0 (j=7 pads); skip t'>=56
// blocks 258+g:   kwb[g][56..63][k]: colsum hi at 56,60; lo at 57,61; 0 else
//                 kbp[g][56..63]: bsum at 56,60; 0 else
__global__ __launch_bounds__(256) void prep_kernel(
    const float* __restrict__ kw, const float* __restrict__ kb,
    const float* __restrict__ reduce_w,
    const float* __restrict__ bn_gamma, const float* __restrict__ bn_beta,
    const float* __restrict__ bn_mean, const float* __restrict__ bn_var,
    ushort* __restrict__ kwb, float* __restrict__ rwT, float* __restrict__ betp,
    float* __restrict__ kbp)
{
    const int bid = blockIdx.x;
    if (bid < 256) {
        int idx  = bid * 256 + threadIdx.x;
        int base = idx * 16;
        int g    = base >> 12;
        int rem  = base & 4095;
        int tp   = rem >> 6;               // t' 0..63
        int k0   = rem & 63;
        if (tp >= 56) return;              // u-region owned by u-blocks
        union { ushort s[16]; uint4 v[2]; } u;
        if ((tp & 7) < 7) {
            int t = (tp >> 3) * 7 + (tp & 7);
            const float* src = kw + ((size_t)(g * KK_ + t)) * HID_ + k0;
            #pragma unroll
            for (int i = 0; i < 16; ++i) u.s[i] = f2bf(src[i]);
        } else {
            #pragma unroll
            for (int i = 0; i < 16; ++i) u.s[i] = 0;
        }
        uint4* dst = (uint4*)(kwb + base);
        dst[0] = u.v[0];
        dst[1] = u.v[1];
    } else if (bid == 256) {
        int k = threadIdx.x;
        #pragma unroll 1
        for (int o = 0; o < HID_; ++o) {
            float inv = bn_gamma[o] * rsqrtf(bn_var[o] + BN_EPS);
            rwT[k * HID_ + o] = reduce_w[o * C_ + k] * inv;
        }
        if (k < HID_) {
            float inv = bn_gamma[k] * rsqrtf(bn_var[k] + BN_EPS);
            betp[k] = bn_beta[k] - bn_mean[k] * inv;
        }
    } else if (bid == 257) {
        for (int i = threadIdx.x; i < G_ * 64; i += 256) {
            int g = i >> 6, tp = i & 63;
            if (tp >= 56) continue;        // u-region
            kbp[i] = ((tp & 7) < 7) ? kb[g * KK_ + (tp >> 3) * 7 + (tp & 7)] : 0.f;
        }
    } else {
        const int g = bid - 258;
        __shared__ float part[4][64];
        const int k  = threadIdx.x & 63;
        const int pr = threadIdx.x >> 6;
        const int t0 = pr * 13;
        const int t1 = (t0 + 13 < KK_) ? t0 + 13 : KK_;
        float s = 0.f;
        for (int t = t0; t < t1; ++t)
            s += kw[((size_t)(g * KK_ + t)) * HID_ + k];
        part[pr][k] = s;
        __syncthreads();
        if (threadIdx.x < 64) {
            float u = part[0][k] + part[1][k] + part[2][k] + part[3][k];
            ushort uh = f2bf(u);
            ushort ul = f2bf(u - bf2f(uh));
            ushort* kg = kwb + (size_t)g * 4096;
            kg[56 * 64 + k] = uh;  kg[60 * 64 + k] = uh;
            kg[57 * 64 + k] = ul;  kg[61 * 64 + k] = ul;
            kg[58 * 64 + k] = 0;   kg[59 * 64 + k] = 0;
            kg[62 * 64 + k] = 0;   kg[63 * 64 + k] = 0;
            float bs = (k < KK_) ? kb[g * KK_ + k] : 0.f;
            #pragma unroll
            for (int off = 32; off >= 1; off >>= 1) bs += __shfl_xor(bs, off);
            if (k == 0) {
                float* bg = kbp + g * 64;
                bg[56] = bs; bg[60] = bs;
                bg[57] = 0.f; bg[58] = 0.f; bg[59] = 0.f;
                bg[61] = 0.f; bg[62] = 0.f; bg[63] = 0.f;
            }
        }
    }
}

// ----------------------------------------------------------------- hv1 ----
__global__ __launch_bounds__(256) void hv1_kernel(
    const float* __restrict__ x, const float* __restrict__ rwT,
    float* __restrict__ hvp, int npx)
{
    const int lane = threadIdx.x & 63;
    const int wq   = __builtin_amdgcn_readfirstlane(threadIdx.x >> 6);
    const int kq   = blockIdx.y;
    const int p    = blockIdx.x * 64 + lane;
    const int b    = p >> 12;
    const int hw   = p & 4095;

    float acc[16];
    #pragma unroll
    for (int j = 0; j < 16; ++j) acc[j] = 0.f;

    const float* xp = x + ((size_t)b * C_ + kq * 64) * HW_ + hw;
    const float* rw = rwT + (kq * 64) * HID_ + wq * 16;
    #pragma unroll 8
    for (int kk = 0; kk < 64; ++kk) {
        float xk = xp[(size_t)kk * HW_];
        #pragma unroll
        for (int j = 0; j < 16; ++j) acc[j] = fmaf(xk, rw[kk * HID_ + j], acc[j]);
    }
    float* dst = hvp + ((size_t)(kq * 64 + wq * 16)) * npx + p;
    #pragma unroll
    for (int j = 0; j < 16; ++j) dst[(size_t)j * npx] = acc[j];
}

// ----------------------------------------------------------------- hv2 ----
__global__ __launch_bounds__(256) void hv2_kernel(
    const float* __restrict__ hvp, const float* __restrict__ betp,
    ushort* __restrict__ hv, int npx)
{
    const int p  = blockIdx.x * 256 + threadIdx.x;
    const int o0 = blockIdx.y * 4;
    ushort s[4];
    #pragma unroll
    for (int j = 0; j < 4; ++j) {
        float v = 0.f;
        #pragma unroll
        for (int kq = 0; kq < 4; ++kq)
            v += hvp[(size_t)(kq * 64 + o0 + j) * npx + p];
        s[j] = f2bf(fmaxf(v + betp[o0 + j], 0.f));
    }
    uint2 w;
    w.x = (uint)s[0] | ((uint)s[1] << 16);
    w.y = (uint)s[2] | ((uint)s[3] << 16);
    *(uint2*)(hv + (size_t)p * HID_ + o0) = w;
}

// --------------------------------------------- tier-2 hv (single-stage) ----
__global__ __launch_bounds__(256) void hv_kernel(
    const float* __restrict__ x, const float* __restrict__ rwT,
    const float* __restrict__ betp, ushort* __restrict__ hv)
{
    const int lane = threadIdx.x & 63;
    const int q    = __builtin_amdgcn_readfirstlane(threadIdx.x >> 6);
    const int p    = blockIdx.x * 64 + lane;
    const int b    = p >> 12;
    const int hw   = p & 4095;
    float acc[16];
    #pragma unroll
    for (int j = 0; j < 16; ++j) acc[j] = betp[q * 16 + j];
    const float* xp = x + (size_t)b * C_ * HW_ + hw;
    #pragma unroll 8
    for (int k = 0; k < C_; ++k) {
        float xk = xp[(size_t)k * HW_];
        const float* rw = rwT + k * HID_ + q * 16;
        #pragma unroll
        for (int j = 0; j < 16; ++j) acc[j] = fmaf(xk, rw[j], acc[j]);
    }
    union { ushort s[16]; uint4 v[2]; } u;
    #pragma unroll
    for (int j = 0; j < 16; ++j) u.s[j] = f2bf(fmaxf(acc[j], 0.f));
    uint4* dst = (uint4*)(hv + (size_t)p * HID_ + q * 16);
    dst[0] = u.v[0];
    dst[1] = u.v[1];
}

// ---------------------------------------------------------------- main ----
// Block = (b, g, quarter). 32x32x16 MFMA, 2 M x 2 N tiles, row-padded taps.
// 16 output rows per block (4 per wave); x_s/hs_s sized for 22 rows.
__global__ __launch_bounds__(256) void invol_main(
    const float* __restrict__ x, const ushort* __restrict__ hv,
    const ushort* __restrict__ kwb, const float* __restrict__ kbp,
    float* __restrict__ out)
{
    __shared__ float x_s[22][72];          // 6336 B, zero-padded window
    __shared__ float hs_s[22][64];         // 5632 B, horizontal 7-sums

    const int tid  = threadIdx.x;
    const int lane = tid & 63;
    const int wave = __builtin_amdgcn_readfirstlane(tid >> 6);
    const int bg   = blockIdx.x;           // b*G + g
    const int b    = bg >> 8;
    const int g    = bg & 255;
    const int y0   = blockIdx.y << 4;      // 0,16,32,48
    const int l31  = lane & 31;
    const int h4   = (lane >> 5) * 4;      // row/col-j offset of this half
    const int kl16 = (lane >> 5) * 16;     // k byte offset of this half
    const int c0   = h4 + l31;             // x_s col base (n-tile 0)

    // ---- stage x quarter-tile (zero-padded rows AND columns) ----
    const float* xg = x + (size_t)bg * HW_;
    for (int idx = tid; idx < 22 * 72; idx += 256) {
        int r = idx / 72, c = idx - r * 72;
        int yy = y0 - 3 + r;
        int cc = c - 3;
        bool v = ((unsigned)yy < 64u) && ((unsigned)cc < 64u);
        x_s[r][c] = v ? xg[yy * 64 + cc] : 0.f;
    }

    // ---- kw A-frags (2 M-tiles x 4 k-steps), once per block ----
    bf16x8 ka[2][4];
    const char* kwg = (const char*)kwb + (size_t)g * 8192;
    #pragma unroll
    for (int m = 0; m < 2; ++m)
        #pragma unroll
        for (int s = 0; s < 4; ++s)
            ka[m][s] = *(const bf16x8*)(kwg + (m * 32 + l31) * 128 + s * 32 + kl16);
    const float* kbg = kbp + g * 64 + h4;  // bias base (per-iter reload)

    __syncthreads();

    // ---- h-pass: regs-first window load, slide in regs (22 rows x 4 grp) ----
    if (tid < 88) {
        int r  = tid >> 2;
        int cc0 = (tid & 3) << 4;
        float v[22];
        #pragma unroll
        for (int i = 0; i < 22; ++i) v[i] = x_s[r][cc0 + i];
        float s = v[0] + v[1] + v[2] + v[3] + v[4] + v[5] + v[6];
        hs_s[r][cc0] = s;
        #pragma unroll
        for (int c = 1; c < 16; ++c) {
            s += v[c + 6] - v[c - 1];
            hs_s[r][cc0 + c] = s;
        }
    }
    __syncthreads();

    const int rowpix0 = (b << 12) + (y0 << 6);

    #pragma unroll 2
    for (int rr = 0; rr < 4; ++rr) {
        const int ry = rr * 4 + wave;      // 0..15

        // hv B-frags for this row: 2 N-tiles x 4 k-steps
        bf16x8 hb0[4], hb1[4];
        const char* hvrow = (const char*)hv + (size_t)(rowpix0 + (ry << 6)) * 128;
        #pragma unroll
        for (int s = 0; s < 4; ++s) {
            hb0[s] = *(const bf16x8*)(hvrow + l31 * 128 + s * 32 + kl16);
            hb1[s] = *(const bf16x8*)(hvrow + (32 + l31) * 128 + s * 32 + kl16);
        }
        // bias (transient: dies at acc init)
        f32x4 kv0[4], kv1[4];
        #pragma unroll
        for (int q = 0; q < 4; ++q) {
            kv0[q] = *(const f32x4*)(kbg + q * 8);
            kv1[q] = *(const f32x4*)(kbg + 32 + q * 8);
        }

        // x2 window sum for own pixel (col = lane)
        float x2 = hs_s[ry][lane] + hs_s[ry + 1][lane] + hs_s[ry + 2][lane]
                 + hs_s[ry + 3][lane] + hs_s[ry + 4][lane]
                 + hs_s[ry + 5][lane] + hs_s[ry + 6][lane];

        // acc init = bias (pad taps get exactly 0)
        f32x16 acc00, acc01, acc10, acc11;
        #pragma unroll
        for (int q = 0; q < 4; ++q)
            #pragma unroll
            for (int e = 0; e < 4; ++e) {
                acc00[q * 4 + e] = kv0[q][e];
                acc01[q * 4 + e] = kv0[q][e];
                acc10[q * 4 + e] = kv1[q][e];
                acc11[q * 4 + e] = kv1[q][e];
            }
        #pragma unroll
        for (int s = 0; s < 4; ++s) {
            acc00 = __builtin_amdgcn_mfma_f32_32x32x16_bf16(ka[0][s], hb0[s], acc00, 0, 0, 0);
            acc01 = __builtin_amdgcn_mfma_f32_32x32x16_bf16(ka[0][s], hb1[s], acc01, 0, 0, 0);
            acc10 = __builtin_amdgcn_mfma_f32_32x32x16_bf16(ka[1][s], hb0[s], acc10, 0, 0, 0);
            acc11 = __builtin_amdgcn_mfma_f32_32x32x16_bf16(ka[1][s], hb1[s], acc11, 0, 0, 0);
        }

        // ssq: m0 all 16 regs + m1 regs 0..11 (pads contribute 0; u-rows excluded)
        float ssq0 = 0.f, ssq1 = 0.f;
        #pragma unroll
        for (int r = 0; r < 16; ++r) {
            ssq0 = fmaf(acc00[r], acc00[r], ssq0);
            ssq1 = fmaf(acc01[r], acc01[r], ssq1);
        }
        #pragma unroll
        for (int r = 0; r < 12; ++r) {
            ssq0 = fmaf(acc10[r], acc10[r], ssq0);
            ssq1 = fmaf(acc11[r], acc11[r], ssq1);
        }
        // mean: u-rows at m1 regs 12/13, SAME regs for both halves
        float mn0 = (acc10[12] + acc10[13]) * (1.f / 49.f);
        float mn1 = (acc11[12] + acc11[13]) * (1.f / 49.f);

        // kx: per quad, 4 consecutive x_s floats in one row (ds_read2 merges)
        float kx0 = 0.f, kx1 = 0.f;
        const float* xb = &x_s[ry][0];
        #pragma unroll
        for (int q = 0; q < 4; ++q) {      // m0: rows i = q
            const float* bp = xb + q * 72 + c0;
            #pragma unroll
            for (int e = 0; e < 4; ++e) {
                kx0 = fmaf(acc00[q * 4 + e], bp[e], kx0);
                kx1 = fmaf(acc01[q * 4 + e], bp[32 + e], kx1);
            }
        }
        #pragma unroll
        for (int q = 0; q < 3; ++q) {      // m1: rows i = 4+q
            const float* bp = xb + (4 + q) * 72 + c0;
            #pragma unroll
            for (int e = 0; e < 4; ++e) {
                kx0 = fmaf(acc10[q * 4 + e], bp[e], kx0);
                kx1 = fmaf(acc11[q * 4 + e], bp[32 + e], kx1);
            }
        }

        // own/cross select + ONE xor32 per quantity
        const bool lo = lane < 32;
        float kx_own = lo ? kx0 : kx1, kx_cr = lo ? kx1 : kx0;
        float ss_own = lo ? ssq0 : ssq1, ss_cr = lo ? ssq1 : ssq0;
        float mo     = lo ? mn0 : mn1;
        float kxo = kx_own + xor32p(kx_cr);
        float sso = ss_own + xor32p(ss_cr);

        float ss = fmaxf(sso - 49.f * mo * mo, 0.f);
        float is = 1.f / fmaxf(sqrtf(ss), 1e-6f);
        out[(size_t)bg * HW_ + ((y0 + ry) << 6) + lane] = (kxo - mo * x2) * is;
    }
}

// ---------------------------------------------------- fallback (no ws) ----
__global__ __launch_bounds__(256) void invol_fallback(
    const float* __restrict__ x, const float* __restrict__ reduce_w,
    const float* __restrict__ bn_gamma, const float* __restrict__ bn_beta,
    const float* __restrict__ bn_mean, const float* __restrict__ bn_var,
    const float* __restrict__ kw, const float* __restrict__ kb,
    float* __restrict__ out)
{
    __shared__ float rwT[C_][HID_ + 4];
    __shared__ float bns[HID_];
    __shared__ float bnb[HID_];
    const int tid = threadIdx.x;
    const int b  = blockIdx.z;
    const int g0 = blockIdx.y * 32;
    const int p  = blockIdx.x * 256 + tid;
    const int py = p >> 6;
    const int px = p & 63;
    #pragma unroll 1
    for (int o = 0; o < HID_; ++o) rwT[tid][o] = reduce_w[o * C_ + tid];
    if (tid < HID_) {
        float inv = bn_gamma[tid] * rsqrtf(bn_var[tid] + BN_EPS);
        bns[tid] = inv;
        bnb[tid] = bn_beta[tid] - bn_mean[tid] * inv;
    }
    __syncthreads();
    float hvv[HID_];
    #pragma unroll
    for (int o = 0; o < HID_; ++o) hvv[o] = 0.f;
    const float* xb = x + (size_t)b * C_ * HW_ + p;
    #pragma unroll 4
    for (int k = 0; k < C_; ++k) {
        float xk = xb[(size_t)k * HW_];
        const float4* wr = (const float4*)&rwT[k][0];
        #pragma unroll
        for (int o4 = 0; o4 < HID_ / 4; ++o4) {
            float4 w = wr[o4];
            hvv[o4*4+0] = fmaf(xk, w.x, hvv[o4*4+0]);
            hvv[o4*4+1] = fmaf(xk, w.y, hvv[o4*4+1]);
            hvv[o4*4+2] = fmaf(xk, w.z, hvv[o4*4+2]);
            hvv[o4*4+3] = fmaf(xk, w.w, hvv[o4*4+3]);
        }
    }
    #pragma unroll
    for (int o = 0; o < HID_; ++o) hvv[o] = fmaxf(fmaf(hvv[o], bns[o], bnb[o]), 0.f);
    #pragma unroll 1
    for (int gi = 0; gi < 32; ++gi) {
        const int g = g0 + gi;
        const float* kwg = kw + (size_t)g * KK_ * HID_;
        float acc[KK_];
        #pragma unroll
        for (int t = 0; t < KK_; ++t) {
            float a = kb[g * KK_ + t];
            const float4* row = (const float4*)(kwg + t * HID_);
            #pragma unroll
            for (int k4 = 0; k4 < HID_ / 4; ++k4) {
                float4 w = row[k4];
                a = fmaf(w.x, hvv[k4*4+0], a);
                a = fmaf(w.y, hvv[k4*4+1], a);
                a = fmaf(w.z, hvv[k4*4+2], a);
                a = fmaf(w.w, hvv[k4*4+3], a);
            }
            acc[t] = a;
        }
        float mean = 0.f;
        #pragma unroll
        for (int t = 0; t < KK_; ++t) mean += acc[t];
        mean *= (1.f / 49.f);
        float ss = 0.f;
        #pragma unroll
        for (int t = 0; t < KK_; ++t) { acc[t] -= mean; ss = fmaf(acc[t], acc[t], ss); }
        float inv = 1.f / fmaxf(sqrtf(ss), 1e-6f);
        const float* xg = x + ((size_t)(b * G_ + g)) * HW_;
        float oacc = 0.f;
        #pragma unroll
        for (int i = 0; i < KS_; ++i) {
            int yv = py + i - 3;
            bool rok = ((unsigned)yv < (unsigned)H_);
            const float* xrow = xg + yv * W_;
            #pragma unroll
            for (int j = 0; j < KS_; ++j) {
                int xx = px + j - 3;
                bool ok = rok && ((unsigned)xx < (unsigned)W_);
                float v = ok ? xrow[xx] : 0.f;
                oacc = fmaf(v, acc[i*7+j], oacc);
            }
        }
        out[((size_t)(b * G_ + g)) * HW_ + p] = oacc * inv;
    }
}

extern "C" void kernel_launch(void* const* d_in, const int* in_sizes, int n_in,
                              void* d_out, int out_size, void* d_ws, size_t ws_size,
                              hipStream_t stream) {
    const float* x        = (const float*)d_in[0];
    const float* reduce_w = (const float*)d_in[1];
    const float* bn_gamma = (const float*)d_in[2];
    const float* bn_beta  = (const float*)d_in[3];
    const float* bn_mean  = (const float*)d_in[4];
    const float* bn_var   = (const float*)d_in[5];
    const float* kproj_w  = (const float*)d_in[6];
    const float* kproj_b  = (const float*)d_in[7];
    float* out = (float*)d_out;
    const int B   = in_sizes[0] / (C_ * HW_);
    const int npx = B * HW_;

    size_t kwb_off = 0;
    size_t kwb_sz  = (size_t)G_ * 64 * 64 * 2;        // 2 MB
    size_t kbp_off = kwb_off + kwb_sz;
    size_t kbp_sz  = (size_t)G_ * 64 * 4;             // 64 KB
    size_t rwt_off = kbp_off + kbp_sz;
    size_t rwt_sz  = (size_t)C_ * HID_ * 4;           // 64 KB
    size_t bet_off = rwt_off + rwt_sz;
    size_t bet_sz  = 256;
    size_t hv_off  = bet_off + bet_sz;
    size_t hv_sz   = (size_t)npx * HID_ * 2;          // 2 MB
    size_t hvp_off = hv_off + hv_sz;
    size_t hvp_sz  = (size_t)4 * HID_ * npx * 4;      // 16 MB
    size_t need2   = hvp_off;                          // without hvp
    size_t need    = hvp_off + hvp_sz;

    if (ws_size < need2) {
        dim3 grid(HW_ / 256, G_ / 32, B);
        invol_fallback<<<grid, 256, 0, stream>>>(x, reduce_w, bn_gamma, bn_beta,
                                                 bn_mean, bn_var, kproj_w, kproj_b, out);
        return;
    }

    ushort* kwb  = (ushort*)((char*)d_ws + kwb_off);
    float*  kbp  = (float*)((char*)d_ws + kbp_off);
    float*  rwT  = (float*)((char*)d_ws + rwt_off);
    float*  betp = (float*)((char*)d_ws + bet_off);
    ushort* hv   = (ushort*)((char*)d_ws + hv_off);
    float*  hvp  = (float*)((char*)d_ws + hvp_off);

    prep_kernel<<<dim3(258 + G_), 256, 0, stream>>>(kproj_w, kproj_b, reduce_w,
                                                    bn_gamma, bn_beta, bn_mean, bn_var,
                                                    kwb, rwT, betp, kbp);
    if (ws_size >= need) {
        hv1_kernel<<<dim3(npx / 64, 4), 256, 0, stream>>>(x, rwT, hvp, npx);
        hv2_kernel<<<dim3(npx / 256, 16), 256, 0, stream>>>(hvp, betp, hv, npx);
    } else {
        hv_kernel<<<dim3(npx / 64), 256, 0, stream>>>(x, rwT, betp, hv);
    }
    invol_main<<<dim3(B * G_, 4), 256, 0, stream>>>(x, hv, kwb, kbp, out);
}

// Round 19
// 124.802 us; speedup vs baseline: 1.1109x; 1.1109x over previous
//
#include <hip/hip_runtime.h>

// Involution via bf16 MFMA tap-GEMM, operand-swapped (D[t][px]), 32x32x16.
// R19: 1-wave blocks. Across R15-R18 occupancy pinned at ~20% (~1.6 blocks/CU)
// regardless of LDS/VGPR; hb prefetch + VALU cuts all flat -> binder is
// block granularity / intra-block wave coupling. Now: 64-thread blocks,
// each (b, g, 16-row stripe); no inter-wave barriers; 16 row-iters/wave;
// LDS 12.3KB -> 13 blocks/CU = 13 independent latency chains per CU.

#define C_    256
#define HID_  64
#define KS_   7
#define KK_   49
#define G_    256
#define H_    64
#define W_    64
#define HW_   4096
#define BN_EPS 1e-5f

typedef __attribute__((ext_vector_type(8)))  short bf16x8;
typedef __attribute__((ext_vector_type(4)))  float f32x4;
typedef __attribute__((ext_vector_type(16))) float f32x16;
typedef __attribute__((ext_vector_type(2)))  unsigned uv2;

__device__ __forceinline__ ushort f2bf(float f) {
    unsigned u = __float_as_uint(f);
    return (ushort)((u + 0x7fffu + ((u >> 16) & 1u)) >> 16);   // RNE
}
__device__ __forceinline__ float bf2f(ushort s) {
    return __uint_as_float((unsigned)s << 16);
}
// v[lane^32] on the VALU pipe, direction-agnostic (pairsum - own). Proven R14/15.
__device__ __forceinline__ float xor32p(float v) {
#if __has_builtin(__builtin_amdgcn_permlane32_swap)
    uv2 r = __builtin_amdgcn_permlane32_swap(__float_as_uint(v), __float_as_uint(v),
                                             false, false);
    return (__uint_as_float(r[0]) + __uint_as_float(r[1])) - v;
#else
    return __shfl_xor(v, 32);
#endif
}

// ---------------------------------------------------------------- prep ----
// Layout: t' = i*8 + j (i,j<7 valid); t'&7==7 -> zero row; t'>=56 -> u-region.
// blocks 0..255:  kwb[g][t'][k] bf16 (valid rows + j=7 zeros; skip t'>=56)
// block 256:      rwT[k][o] = reduce_w[o][k]*bn_inv[o]; betp[o]
// block 257:      kbp[g][t'] = bias (valid), 0 (j=7 pads); skip t'>=56
// blocks 258+g:   kwb[g][56..63][k]: colsum hi at 56,60; lo at 57,61; 0 else
//                 kbp[g][56..63]: bsum at 56,60; 0 else
__global__ __launch_bounds__(256) void prep_kernel(
    const float* __restrict__ kw, const float* __restrict__ kb,
    const float* __restrict__ reduce_w,
    const float* __restrict__ bn_gamma, const float* __restrict__ bn_beta,
    const float* __restrict__ bn_mean, const float* __restrict__ bn_var,
    ushort* __restrict__ kwb, float* __restrict__ rwT, float* __restrict__ betp,
    float* __restrict__ kbp)
{
    const int bid = blockIdx.x;
    if (bid < 256) {
        int idx  = bid * 256 + threadIdx.x;
        int base = idx * 16;
        int g    = base >> 12;
        int rem  = base & 4095;
        int tp   = rem >> 6;               // t' 0..63
        int k0   = rem & 63;
        if (tp >= 56) return;              // u-region owned by u-blocks
        union { ushort s[16]; uint4 v[2]; } u;
        if ((tp & 7) < 7) {
            int t = (tp >> 3) * 7 + (tp & 7);
            const float* src = kw + ((size_t)(g * KK_ + t)) * HID_ + k0;
            #pragma unroll
            for (int i = 0; i < 16; ++i) u.s[i] = f2bf(src[i]);
        } else {
            #pragma unroll
            for (int i = 0; i < 16; ++i) u.s[i] = 0;
        }
        uint4* dst = (uint4*)(kwb + base);
        dst[0] = u.v[0];
        dst[1] = u.v[1];
    } else if (bid == 256) {
        int k = threadIdx.x;
        #pragma unroll 1
        for (int o = 0; o < HID_; ++o) {
            float inv = bn_gamma[o] * rsqrtf(bn_var[o] + BN_EPS);
            rwT[k * HID_ + o] = reduce_w[o * C_ + k] * inv;
        }
        if (k < HID_) {
            float inv = bn_gamma[k] * rsqrtf(bn_var[k] + BN_EPS);
            betp[k] = bn_beta[k] - bn_mean[k] * inv;
        }
    } else if (bid == 257) {
        for (int i = threadIdx.x; i < G_ * 64; i += 256) {
            int g = i >> 6, tp = i & 63;
            if (tp >= 56) continue;        // u-region
            kbp[i] = ((tp & 7) < 7) ? kb[g * KK_ + (tp >> 3) * 7 + (tp & 7)] : 0.f;
        }
    } else {
        const int g = bid - 258;
        __shared__ float part[4][64];
        const int k  = threadIdx.x & 63;
        const int pr = threadIdx.x >> 6;
        const int t0 = pr * 13;
        const int t1 = (t0 + 13 < KK_) ? t0 + 13 : KK_;
        float s = 0.f;
        for (int t = t0; t < t1; ++t)
            s += kw[((size_t)(g * KK_ + t)) * HID_ + k];
        part[pr][k] = s;
        __syncthreads();
        if (threadIdx.x < 64) {
            float u = part[0][k] + part[1][k] + part[2][k] + part[3][k];
            ushort uh = f2bf(u);
            ushort ul = f2bf(u - bf2f(uh));
            ushort* kg = kwb + (size_t)g * 4096;
            kg[56 * 64 + k] = uh;  kg[60 * 64 + k] = uh;
            kg[57 * 64 + k] = ul;  kg[61 * 64 + k] = ul;
            kg[58 * 64 + k] = 0;   kg[59 * 64 + k] = 0;
            kg[62 * 64 + k] = 0;   kg[63 * 64 + k] = 0;
            float bs = (k < KK_) ? kb[g * KK_ + k] : 0.f;
            #pragma unroll
            for (int off = 32; off >= 1; off >>= 1) bs += __shfl_xor(bs, off);
            if (k == 0) {
                float* bg = kbp + g * 64;
                bg[56] = bs; bg[60] = bs;
                bg[57] = 0.f; bg[58] = 0.f; bg[59] = 0.f;
                bg[61] = 0.f; bg[62] = 0.f; bg[63] = 0.f;
            }
        }
    }
}

// ----------------------------------------------------------------- hv1 ----
__global__ __launch_bounds__(256) void hv1_kernel(
    const float* __restrict__ x, const float* __restrict__ rwT,
    float* __restrict__ hvp, int npx)
{
    const int lane = threadIdx.x & 63;
    const int wq   = __builtin_amdgcn_readfirstlane(threadIdx.x >> 6);
    const int kq   = blockIdx.y;
    const int p    = blockIdx.x * 64 + lane;
    const int b    = p >> 12;
    const int hw   = p & 4095;

    float acc[16];
    #pragma unroll
    for (int j = 0; j < 16; ++j) acc[j] = 0.f;

    const float* xp = x + ((size_t)b * C_ + kq * 64) * HW_ + hw;
    const float* rw = rwT + (kq * 64) * HID_ + wq * 16;
    #pragma unroll 8
    for (int kk = 0; kk < 64; ++kk) {
        float xk = xp[(size_t)kk * HW_];
        #pragma unroll
        for (int j = 0; j < 16; ++j) acc[j] = fmaf(xk, rw[kk * HID_ + j], acc[j]);
    }
    float* dst = hvp + ((size_t)(kq * 64 + wq * 16)) * npx + p;
    #pragma unroll
    for (int j = 0; j < 16; ++j) dst[(size_t)j * npx] = acc[j];
}

// ----------------------------------------------------------------- hv2 ----
__global__ __launch_bounds__(256) void hv2_kernel(
    const float* __restrict__ hvp, const float* __restrict__ betp,
    ushort* __restrict__ hv, int npx)
{
    const int p  = blockIdx.x * 256 + threadIdx.x;
    const int o0 = blockIdx.y * 4;
    ushort s[4];
    #pragma unroll
    for (int j = 0; j < 4; ++j) {
        float v = 0.f;
        #pragma unroll
        for (int kq = 0; kq < 4; ++kq)
            v += hvp[(size_t)(kq * 64 + o0 + j) * npx + p];
        s[j] = f2bf(fmaxf(v + betp[o0 + j], 0.f));
    }
    uint2 w;
    w.x = (uint)s[0] | ((uint)s[1] << 16);
    w.y = (uint)s[2] | ((uint)s[3] << 16);
    *(uint2*)(hv + (size_t)p * HID_ + o0) = w;
}

// --------------------------------------------- tier-2 hv (single-stage) ----
__global__ __launch_bounds__(256) void hv_kernel(
    const float* __restrict__ x, const float* __restrict__ rwT,
    const float* __restrict__ betp, ushort* __restrict__ hv)
{
    const int lane = threadIdx.x & 63;
    const int q    = __builtin_amdgcn_readfirstlane(threadIdx.x >> 6);
    const int p    = blockIdx.x * 64 + lane;
    const int b    = p >> 12;
    const int hw   = p & 4095;
    float acc[16];
    #pragma unroll
    for (int j = 0; j < 16; ++j) acc[j] = betp[q * 16 + j];
    const float* xp = x + (size_t)b * C_ * HW_ + hw;
    #pragma unroll 8
    for (int k = 0; k < C_; ++k) {
        float xk = xp[(size_t)k * HW_];
        const float* rw = rwT + k * HID_ + q * 16;
        #pragma unroll
        for (int j = 0; j < 16; ++j) acc[j] = fmaf(xk, rw[j], acc[j]);
    }
    union { ushort s[16]; uint4 v[2]; } u;
    #pragma unroll
    for (int j = 0; j < 16; ++j) u.s[j] = f2bf(fmaxf(acc[j], 0.f));
    uint4* dst = (uint4*)(hv + (size_t)p * HID_ + q * 16);
    dst[0] = u.v[0];
    dst[1] = u.v[1];
}

// ---------------------------------------------------------------- main ----
// Block = 1 wave = (b, g, 16-row stripe). 32x32x16 MFMA, 2Mx2N tiles,
// row-padded taps. No inter-wave coupling; 16 row-iters per wave.
__global__ __launch_bounds__(64) void invol_main(
    const float* __restrict__ x, const ushort* __restrict__ hv,
    const ushort* __restrict__ kwb, const float* __restrict__ kbp,
    float* __restrict__ out)
{
    __shared__ float x_s[22][72];          // 6336 B, zero-padded window
    __shared__ float hs_s[22][64];         // 5632 B, horizontal 7-sums

    const int lane = threadIdx.x;          // 0..63
    const int bg   = blockIdx.x;           // b*G + g
    const int b    = bg >> 8;
    const int g    = bg & 255;
    const int y0   = blockIdx.y << 4;      // 0,16,32,48
    const int l31  = lane & 31;
    const int h4   = (lane >> 5) * 4;      // row/col-j offset of this half
    const int kl16 = (lane >> 5) * 16;     // k byte offset of this half
    const int c0   = h4 + l31;             // x_s col base (n-tile 0)

    // ---- stage x stripe (zero-padded rows AND columns) ----
    const float* xg = x + (size_t)bg * HW_;
    for (int idx = lane; idx < 22 * 72; idx += 64) {
        int r = idx / 72, c = idx - r * 72;
        int yy = y0 - 3 + r;
        int cc = c - 3;
        bool v = ((unsigned)yy < 64u) && ((unsigned)cc < 64u);
        x_s[r][c] = v ? xg[yy * 64 + cc] : 0.f;
    }

    // ---- kw A-frags (2 M-tiles x 4 k-steps), once per block ----
    bf16x8 ka[2][4];
    const char* kwg = (const char*)kwb + (size_t)g * 8192;
    #pragma unroll
    for (int m = 0; m < 2; ++m)
        #pragma unroll
        for (int s = 0; s < 4; ++s)
            ka[m][s] = *(const bf16x8*)(kwg + (m * 32 + l31) * 128 + s * 32 + kl16);
    const float* kbg = kbp + g * 64 + h4;  // bias base (per-iter reload)

    __syncthreads();                        // single wave: cheap

    // ---- h-pass: 88 tasks over 64 lanes, regs-first sliding window ----
    for (int t = lane; t < 88; t += 64) {
        int r   = t >> 2;
        int cc0 = (t & 3) << 4;
        float v[22];
        #pragma unroll
        for (int i = 0; i < 22; ++i) v[i] = x_s[r][cc0 + i];
        float s = v[0] + v[1] + v[2] + v[3] + v[4] + v[5] + v[6];
        hs_s[r][cc0] = s;
        #pragma unroll
        for (int c = 1; c < 16; ++c) {
            s += v[c + 6] - v[c - 1];
            hs_s[r][cc0 + c] = s;
        }
    }
    __syncthreads();

    const int rowpix0 = (b << 12) + (y0 << 6);

    #pragma unroll 2
    for (int ry = 0; ry < 16; ++ry) {
        // hv B-frags for this row: 2 N-tiles x 4 k-steps
        bf16x8 hb0[4], hb1[4];
        const char* hvrow = (const char*)hv + (size_t)(rowpix0 + (ry << 6)) * 128;
        #pragma unroll
        for (int s = 0; s < 4; ++s) {
            hb0[s] = *(const bf16x8*)(hvrow + l31 * 128 + s * 32 + kl16);
            hb1[s] = *(const bf16x8*)(hvrow + (32 + l31) * 128 + s * 32 + kl16);
        }
        // bias (transient: dies at acc init)
        f32x4 kv0[4], kv1[4];
        #pragma unroll
        for (int q = 0; q < 4; ++q) {
            kv0[q] = *(const f32x4*)(kbg + q * 8);
            kv1[q] = *(const f32x4*)(kbg + 32 + q * 8);
        }

        // x2 window sum for own pixel (col = lane)
        float x2 = hs_s[ry][lane] + hs_s[ry + 1][lane] + hs_s[ry + 2][lane]
                 + hs_s[ry + 3][lane] + hs_s[ry + 4][lane]
                 + hs_s[ry + 5][lane] + hs_s[ry + 6][lane];

        // acc init = bias (pad taps get exactly 0)
        f32x16 acc00, acc01, acc10, acc11;
        #pragma unroll
        for (int q = 0; q < 4; ++q)
            #pragma unroll
            for (int e = 0; e < 4; ++e) {
                acc00[q * 4 + e] = kv0[q][e];
                acc01[q * 4 + e] = kv0[q][e];
                acc10[q * 4 + e] = kv1[q][e];
                acc11[q * 4 + e] = kv1[q][e];
            }
        #pragma unroll
        for (int s = 0; s < 4; ++s) {
            acc00 = __builtin_amdgcn_mfma_f32_32x32x16_bf16(ka[0][s], hb0[s], acc00, 0, 0, 0);
            acc01 = __builtin_amdgcn_mfma_f32_32x32x16_bf16(ka[0][s], hb1[s], acc01, 0, 0, 0);
            acc10 = __builtin_amdgcn_mfma_f32_32x32x16_bf16(ka[1][s], hb0[s], acc10, 0, 0, 0);
            acc11 = __builtin_amdgcn_mfma_f32_32x32x16_bf16(ka[1][s], hb1[s], acc11, 0, 0, 0);
        }

        // ssq: m0 all 16 regs + m1 regs 0..11 (pads contribute 0)
        float ssq0 = 0.f, ssq1 = 0.f;
        #pragma unroll
        for (int r = 0; r < 16; ++r) {
            ssq0 = fmaf(acc00[r], acc00[r], ssq0);
            ssq1 = fmaf(acc01[r], acc01[r], ssq1);
        }
        #pragma unroll
        for (int r = 0; r < 12; ++r) {
            ssq0 = fmaf(acc10[r], acc10[r], ssq0);
            ssq1 = fmaf(acc11[r], acc11[r], ssq1);
        }
        // mean: u-rows at m1 regs 12/13, SAME regs for both halves
        float mn0 = (acc10[12] + acc10[13]) * (1.f / 49.f);
        float mn1 = (acc11[12] + acc11[13]) * (1.f / 49.f);

        // kx: per quad, 4 consecutive x_s floats in one row (ds_read2 merges)
        float kx0 = 0.f, kx1 = 0.f;
        const float* xb = &x_s[ry][0];
        #pragma unroll
        for (int q = 0; q < 4; ++q) {      // m0: rows i = q
            const float* bp = xb + q * 72 + c0;
            #pragma unroll
            for (int e = 0; e < 4; ++e) {
                kx0 = fmaf(acc00[q * 4 + e], bp[e], kx0);
                kx1 = fmaf(acc01[q * 4 + e], bp[32 + e], kx1);
            }
        }
        #pragma unroll
        for (int q = 0; q < 3; ++q) {      // m1: rows i = 4+q
            const float* bp = xb + (4 + q) * 72 + c0;
            #pragma unroll
            for (int e = 0; e < 4; ++e) {
                kx0 = fmaf(acc10[q * 4 + e], bp[e], kx0);
                kx1 = fmaf(acc11[q * 4 + e], bp[32 + e], kx1);
            }
        }

        // own/cross select + ONE xor32 per quantity
        const bool lo = lane < 32;
        float kx_own = lo ? kx0 : kx1, kx_cr = lo ? kx1 : kx0;
        float ss_own = lo ? ssq0 : ssq1, ss_cr = lo ? ssq1 : ssq0;
        float mo     = lo ? mn0 : mn1;
        float kxo = kx_own + xor32p(kx_cr);
        float sso = ss_own + xor32p(ss_cr);

        float ss = fmaxf(sso - 49.f * mo * mo, 0.f);
        float is = 1.f / fmaxf(sqrtf(ss), 1e-6f);
        out[(size_t)bg * HW_ + ((y0 + ry) << 6) + lane] = (kxo - mo * x2) * is;
    }
}

// ---------------------------------------------------- fallback (no ws) ----
__global__ __launch_bounds__(256) void invol_fallback(
    const float* __restrict__ x, const float* __restrict__ reduce_w,
    const float* __restrict__ bn_gamma, const float* __restrict__ bn_beta,
    const float* __restrict__ bn_mean, const float* __restrict__ bn_var,
    const float* __restrict__ kw, const float* __restrict__ kb,
    float* __restrict__ out)
{
    __shared__ float rwT[C_][HID_ + 4];
    __shared__ float bns[HID_];
    __shared__ float bnb[HID_];
    const int tid = threadIdx.x;
    const int b  = blockIdx.z;
    const int g0 = blockIdx.y * 32;
    const int p  = blockIdx.x * 256 + tid;
    const int py = p >> 6;
    const int px = p & 63;
    #pragma unroll 1
    for (int o = 0; o < HID_; ++o) rwT[tid][o] = reduce_w[o * C_ + tid];
    if (tid < HID_) {
        float inv = bn_gamma[tid] * rsqrtf(bn_var[tid] + BN_EPS);
        bns[tid] = inv;
        bnb[tid] = bn_beta[tid] - bn_mean[tid] * inv;
    }
    __syncthreads();
    float hvv[HID_];
    #pragma unroll
    for (int o = 0; o < HID_; ++o) hvv[o] = 0.f;
    const float* xb = x + (size_t)b * C_ * HW_ + p;
    #pragma unroll 4
    for (int k = 0; k < C_; ++k) {
        float xk = xb[(size_t)k * HW_];
        const float4* wr = (const float4*)&rwT[k][0];
        #pragma unroll
        for (int o4 = 0; o4 < HID_ / 4; ++o4) {
            float4 w = wr[o4];
            hvv[o4*4+0] = fmaf(xk, w.x, hvv[o4*4+0]);
            hvv[o4*4+1] = fmaf(xk, w.y, hvv[o4*4+1]);
            hvv[o4*4+2] = fmaf(xk, w.z, hvv[o4*4+2]);
            hvv[o4*4+3] = fmaf(xk, w.w, hvv[o4*4+3]);
        }
    }
    #pragma unroll
    for (int o = 0; o < HID_; ++o) hvv[o] = fmaxf(fmaf(hvv[o], bns[o], bnb[o]), 0.f);
    #pragma unroll 1
    for (int gi = 0; gi < 32; ++gi) {
        const int g = g0 + gi;
        const float* kwg = kw + (size_t)g * KK_ * HID_;
        float acc[KK_];
        #pragma unroll
        for (int t = 0; t < KK_; ++t) {
            float a = kb[g * KK_ + t];
            const float4* row = (const float4*)(kwg + t * HID_);
            #pragma unroll
            for (int k4 = 0; k4 < HID_ / 4; ++k4) {
                float4 w = row[k4];
                a = fmaf(w.x, hvv[k4*4+0], a);
                a = fmaf(w.y, hvv[k4*4+1], a);
                a = fmaf(w.z, hvv[k4*4+2], a);
                a = fmaf(w.w, hvv[k4*4+3], a);
            }
            acc[t] = a;
        }
        float mean = 0.f;
        #pragma unroll
        for (int t = 0; t < KK_; ++t) mean += acc[t];
        mean *= (1.f / 49.f);
        float ss = 0.f;
        #pragma unroll
        for (int t = 0; t < KK_; ++t) { acc[t] -= mean; ss = fmaf(acc[t], acc[t], ss); }
        float inv = 1.f / fmaxf(sqrtf(ss), 1e-6f);
        const float* xg = x + ((size_t)(b * G_ + g)) * HW_;
        float oacc = 0.f;
        #pragma unroll
        for (int i = 0; i < KS_; ++i) {
            int yv = py + i - 3;
            bool rok = ((unsigned)yv < (unsigned)H_);
            const float* xrow = xg + yv * W_;
            #pragma unroll
            for (int j = 0; j < KS_; ++j) {
                int xx = px + j - 3;
                bool ok = rok && ((unsigned)xx < (unsigned)W_);
                float v = ok ? xrow[xx] : 0.f;
                oacc = fmaf(v, acc[i*7+j], oacc);
            }
        }
        out[((size_t)(b * G_ + g)) * HW_ + p] = oacc * inv;
    }
}

extern "C" void kernel_launch(void* const* d_in, const int* in_sizes, int n_in,
                              void* d_out, int out_size, void* d_ws, size_t ws_size,
                              hipStream_t stream) {
    const float* x        = (const float*)d_in[0];
    const float* reduce_w = (const float*)d_in[1];
    const float* bn_gamma = (const float*)d_in[2];
    const float* bn_beta  = (const float*)d_in[3];
    const float* bn_mean  = (const float*)d_in[4];
    const float* bn_var   = (const float*)d_in[5];
    const float* kproj_w  = (const float*)d_in[6];
    const float* kproj_b  = (const float*)d_in[7];
    float* out = (float*)d_out;
    const int B   = in_sizes[0] / (C_ * HW_);
    const int npx = B * HW_;

    size_t kwb_off = 0;
    size_t kwb_sz  = (size_t)G_ * 64 * 64 * 2;        // 2 MB
    size_t kbp_off = kwb_off + kwb_sz;
    size_t kbp_sz  = (size_t)G_ * 64 * 4;             // 64 KB
    size_t rwt_off = kbp_off + kbp_sz;
    size_t rwt_sz  = (size_t)C_ * HID_ * 4;           // 64 KB
    size_t bet_off = rwt_off + rwt_sz;
    size_t bet_sz  = 256;
    size_t hv_off  = bet_off + bet_sz;
    size_t hv_sz   = (size_t)npx * HID_ * 2;          // 2 MB
    size_t hvp_off = hv_off + hv_sz;
    size_t hvp_sz  = (size_t)4 * HID_ * npx * 4;      // 16 MB
    size_t need2   = hvp_off;                          // without hvp
    size_t need    = hvp_off + hvp_sz;

    if (ws_size < need2) {
        dim3 grid(HW_ / 256, G_ / 32, B);
        invol_fallback<<<grid, 256, 0, stream>>>(x, reduce_w, bn_gamma, bn_beta,
                                                 bn_mean, bn_var, kproj_w, kproj_b, out);
        return;
    }

    ushort* kwb  = (ushort*)((char*)d_ws + kwb_off);
    float*  kbp  = (float*)((char*)d_ws + kbp_off);
    float*  rwT  = (float*)((char*)d_ws + rwt_off);
    float*  betp = (float*)((char*)d_ws + bet_off);
    ushort* hv   = (ushort*)((char*)d_ws + hv_off);
    float*  hvp  = (float*)((char*)d_ws + hvp_off);

    prep_kernel<<<dim3(258 + G_), 256, 0, stream>>>(kproj_w, kproj_b, reduce_w,
                                                    bn_gamma, bn_beta, bn_mean, bn_var,
                                                    kwb, rwT, betp, kbp);
    if (ws_size >= need) {
        hv1_kernel<<<dim3(npx / 64, 4), 256, 0, stream>>>(x, rwT, hvp, npx);
        hv2_kernel<<<dim3(npx / 256, 16), 256, 0, stream>>>(hvp, betp, hv, npx);
    } else {
        hv_kernel<<<dim3(npx / 64), 256, 0, stream>>>(x, rwT, betp, hv);
    }
    invol_main<<<dim3(B * G_, 4), 64, 0, stream>>>(x, hv, kwb, kbp, out);
}